// Round 1
// baseline (44.375 us; speedup 1.0000x reference)
//
#include <hip/hip_runtime.h>

// Problem dims (fixed by harness setup_inputs)
#define NB 4
#define WR 320
#define NH 240
#define WL 320
#define NLEV 4
#define NK 9
#define TW 64                       // wl columns per block
#define NTILES (WL / TW)            // 5
#define BAND_LO 96                  // rows staged before w0
#define BAND_HI 104                 // rows staged after w0 (exclusive)
#define MAXROWS (BAND_LO + BAND_HI) // 200
#define RSTRIDE ((size_t)NH * WL)   // 76800 floats: corr r-stride == out plane stride

typedef const __attribute__((address_space(1))) void* gas_t;
typedef __attribute__((address_space(3))) void* las_t;

__device__ __forceinline__ void gld_lds16(const float* g, float* l) {
  // async global->LDS, 16B/lane; LDS dest is wave-uniform base + lane*16
  __builtin_amdgcn_global_load_lds((gas_t)g, (las_t)l, 16, 0, 0);
}

template <int L>
__device__ __forceinline__ void sample_level(const float* __restrict__ lds,
                                             int c, int row_lo, float idx_c,
                                             float* __restrict__ outp) {
  const int Wrl = WR >> L;
  const int Wm1 = Wrl - 1;
  const float sc = 1.0f / (float)(1 << L);
  const float fidx = idx_c * sc;

  auto pooled = [&](int j) -> float {
    const int r = (j << L) - row_lo;
    float s = lds[r * TW + c];
#pragma unroll
    for (int t = 1; t < (1 << L); ++t) s += lds[(r + t) * TW + c];
    return s * sc;
  };

  // k=0 index; i0 sequence is non-decreasing with steps in {0,1}
  float idk = fminf(fmaxf(fidx - 4.0f, 0.0f), (float)Wm1);
  int j = (int)idk;
  float vA = pooled(j);
  float vB = pooled(min(j + 1, Wm1));

#pragma unroll
  for (int k = 0; k < NK; ++k) {
    const float idx = fminf(fmaxf(fidx + (float)(k - 4), 0.0f), (float)Wm1);
    const int i0 = (int)idx;
    if (i0 != j) {  // slide the (vA,vB) window
      vA = vB;
      vB = pooled(min(i0 + 1, Wm1));
      j = i0;
    }
    const float w = idx - (float)i0;
    outp[(size_t)k * RSTRIDE] = fmaf(w, vB - vA, vA);
  }
}

extern "C" __global__ __launch_bounds__(256) void corr_sample_kernel(
    const float* __restrict__ corr, const float* __restrict__ disp,
    float* __restrict__ out) {
  __shared__ float lds0[MAXROWS * TW];

  const int bid = blockIdx.x;
  const int tile = bid % NTILES;
  const int h = (bid / NTILES) % NH;
  const int b = bid / (NTILES * NH);
  const int w0 = tile * TW;

  const int row_lo = max(0, w0 - BAND_LO);
  const int row_hi = min(WR, w0 + BAND_HI);  // rows count is a multiple of 4

  const int tid = (int)threadIdx.x;
  const int lane = tid & 63;
  const int wv = tid >> 6;  // wave id == pyramid level

  // ---- stage band rows [row_lo, row_hi) x [w0, w0+64) into LDS ----
  // one global_load_lds_dwordx4 per wave stages 4 rows (16 lanes/row)
  const float* src0 = corr + (size_t)b * WR * RSTRIDE + (size_t)h * WL + w0;
  {
    const int sub = lane >> 4;         // row within 4-row group
    const int c4 = (lane & 15) << 2;   // float col within row
    for (int r0 = row_lo + wv * 4; r0 < row_hi; r0 += 16) {
      const float* g = src0 + (size_t)(r0 + sub) * RSTRIDE + c4;
      gld_lds16(g, &lds0[(r0 - row_lo) * TW]);
    }
  }
  asm volatile("s_waitcnt vmcnt(0)" ::: "memory");
  __syncthreads();

  // ---- sample: wave wv handles level wv for all 64 columns ----
  const int c = lane;
  const float dsp = disp[((size_t)b * NH + h) * WL + w0 + c];
  const float idx_c = (float)(w0 + c) - dsp;
  float* outp =
      out + ((size_t)(b * (NLEV * NK) + wv * NK) * NH + h) * WL + w0 + c;

  switch (wv) {
    case 0: sample_level<0>(lds0, c, row_lo, idx_c, outp); break;
    case 1: sample_level<1>(lds0, c, row_lo, idx_c, outp); break;
    case 2: sample_level<2>(lds0, c, row_lo, idx_c, outp); break;
    default: sample_level<3>(lds0, c, row_lo, idx_c, outp); break;
  }
}

extern "C" void kernel_launch(void* const* d_in, const int* in_sizes, int n_in,
                              void* d_out, int out_size, void* d_ws,
                              size_t ws_size, hipStream_t stream) {
  const float* corr = (const float*)d_in[0];
  const float* disp = (const float*)d_in[1];
  float* out = (float*)d_out;
  const int grid = NB * NH * NTILES;  // 4800 blocks
  corr_sample_kernel<<<grid, 256, 0, stream>>>(corr, disp, out);
}

// Round 2
// 44.159 us; speedup vs baseline: 1.0049x; 1.0049x over previous
//
#include <hip/hip_runtime.h>

// Problem dims (fixed by harness setup_inputs)
#define NB 4
#define WR 320
#define NH 240
#define WL 320
#define NLEV 4
#define NK 9
#define TW 32                       // wl columns per block
#define NTILES (WL / TW)            // 10
#define BAND_LO 96                  // rows staged before w0
#define BAND_HI 72                  // rows staged after w0 (exclusive), TW=32
#define MAXROWS (BAND_LO + BAND_HI) // 168
#define RSTRIDE ((size_t)NH * WL)   // 76800 floats: corr r-stride == out plane stride

typedef const __attribute__((address_space(1))) void* gas_t;
typedef __attribute__((address_space(3))) void* las_t;

__device__ __forceinline__ void gld_lds16(const float* g, float* l) {
  // async global->LDS, 16B/lane; LDS dest is wave-uniform base + lane*16
  __builtin_amdgcn_global_load_lds((gas_t)g, (las_t)l, 16, 0, 0);
}

template <int L>
__device__ __forceinline__ void sample_level(const float* __restrict__ lds,
                                             int c, int row_lo, float idx_c,
                                             float* __restrict__ outp) {
  const int Wrl = WR >> L;
  const int Wm1 = Wrl - 1;
  const float sc = 1.0f / (float)(1 << L);
  const float fidx = idx_c * sc;

  auto pooled = [&](int j) -> float {
    const int r = (j << L) - row_lo;
    float s = lds[r * TW + c];
#pragma unroll
    for (int t = 1; t < (1 << L); ++t) s += lds[(r + t) * TW + c];
    return s * sc;
  };

  // k=0 index; i0 sequence is non-decreasing with steps in {0,1}
  float idk = fminf(fmaxf(fidx - 4.0f, 0.0f), (float)Wm1);
  int j = (int)idk;
  float vA = pooled(j);
  float vB = pooled(min(j + 1, Wm1));

#pragma unroll
  for (int k = 0; k < NK; ++k) {
    const float idx = fminf(fmaxf(fidx + (float)(k - 4), 0.0f), (float)Wm1);
    const int i0 = (int)idx;
    if (i0 != j) {  // slide the (vA,vB) window
      vA = vB;
      vB = pooled(min(i0 + 1, Wm1));
      j = i0;
    }
    const float w = idx - (float)i0;
    outp[(size_t)k * RSTRIDE] = fmaf(w, vB - vA, vA);
  }
}

extern "C" __global__ __launch_bounds__(128) void corr_sample_kernel(
    const float* __restrict__ corr, const float* __restrict__ disp,
    float* __restrict__ out) {
  __shared__ float lds0[MAXROWS * TW];

  const int bid = blockIdx.x;
  const int tile = bid % NTILES;
  const int h = (bid / NTILES) % NH;
  const int b = bid / (NTILES * NH);
  const int w0 = tile * TW;

  const int row_lo = max(0, w0 - BAND_LO);
  const int row_hi = min(WR, w0 + BAND_HI);  // bounds are multiples of 8

  const int tid = (int)threadIdx.x;
  const int lane = tid & 63;
  const int wv = tid >> 6;          // wave id (0..1)
  const int half = (tid >> 5) & 1;  // half-wave id
  const int c = tid & 31;           // column within tile

  // ---- stage band rows [row_lo, row_hi) x [w0, w0+32) into LDS ----
  // one global_load_lds_dwordx4 per wave stages 8 rows (8 lanes/row, 128B/row)
  const float* src0 = corr + (size_t)b * WR * RSTRIDE + (size_t)h * WL + w0;
  {
    const int sub = lane >> 3;        // row within 8-row group
    const int c4 = (lane & 7) << 2;   // float col within row
    for (int r0 = row_lo + wv * 8; r0 < row_hi; r0 += 16) {
      const float* g = src0 + (size_t)(r0 + sub) * RSTRIDE + c4;
      gld_lds16(g, &lds0[(r0 - row_lo) * TW]);
    }
  }
  asm volatile("s_waitcnt vmcnt(0)" ::: "memory");
  __syncthreads();

  // ---- sample: half-wave (wv,half) handles one level for 32 columns ----
  // wave0 = levels {0,3}, wave1 = {1,2} (balances LDS-read issue count)
  const int L = (wv == 0) ? (half == 0 ? 0 : 3) : (half == 0 ? 1 : 2);
  const float dsp = disp[((size_t)b * NH + h) * WL + w0 + c];
  const float idx_c = (float)(w0 + c) - dsp;
  float* outp =
      out + ((size_t)(b * (NLEV * NK) + L * NK) * NH + h) * WL + w0 + c;

  switch (L) {
    case 0: sample_level<0>(lds0, c, row_lo, idx_c, outp); break;
    case 1: sample_level<1>(lds0, c, row_lo, idx_c, outp); break;
    case 2: sample_level<2>(lds0, c, row_lo, idx_c, outp); break;
    default: sample_level<3>(lds0, c, row_lo, idx_c, outp); break;
  }
}

extern "C" void kernel_launch(void* const* d_in, const int* in_sizes, int n_in,
                              void* d_out, int out_size, void* d_ws,
                              size_t ws_size, hipStream_t stream) {
  const float* corr = (const float*)d_in[0];
  const float* disp = (const float*)d_in[1];
  float* out = (float*)d_out;
  const int grid = NB * NH * NTILES;  // 9600 blocks
  corr_sample_kernel<<<grid, 128, 0, stream>>>(corr, disp, out);
}